// Round 6
// baseline (1965.937 us; speedup 1.0000x reference)
//
#include <hip/hip_runtime.h>

#define NB 8
#define CAP 128
#define NFEAT 704
#define MSLICE 8            // node slices per (batch,k) in moments
#define PSLICE (MSLICE * 4) // partial slots = slices * subs

// ---------------- setup kernels ----------------

__global__ void count_edges(const int* __restrict__ ei, int E, int* __restrict__ cnt) {
    int e = blockIdx.x * blockDim.x + threadIdx.x;
    if (e < E) atomicAdd(&cnt[ei[E + e]], 1);
}

__global__ void compute_dinv(const int* __restrict__ cnt, float* __restrict__ dinv, int n) {
    int v = blockIdx.x * blockDim.x + threadIdx.x;
    if (v < n) dinv[v] = rsqrtf((float)(cnt[v] + 1));  // +1 self-loop; always > 0
}

__global__ void fill_edges(const int* __restrict__ ei, int E, const float* __restrict__ dinv,
                           int* __restrict__ cursor, int2* __restrict__ pairs) {
    int e = blockIdx.x * blockDim.x + threadIdx.x;
    if (e < E) {
        int r = ei[e], c = ei[E + e];
        int pos = atomicAdd(&cursor[c], 1);
        if (pos < CAP) {
            float w = dinv[r] * dinv[c];
            pairs[(size_t)c * CAP + pos] = make_int2(r, __float_as_int(w));
        }
    }
}

// pad each node's edge list to a multiple of 8 with zero-weight edges
__global__ void pad_edges(const int* __restrict__ cnt, int2* __restrict__ pairs, int n) {
    int v = blockIdx.x * blockDim.x + threadIdx.x;
    if (v >= n) return;
    int c = min(cnt[v], CAP);
    int c8 = (c + 7) & ~7;
    for (int j = c; j < c8; ++j) pairs[(size_t)v * CAP + j] = make_int2(0, 0);
}

// batch is SORTED: boundaries, no atomics
__global__ void batch_bounds(const int* __restrict__ batch, int n, int* __restrict__ boff) {
    int i = blockIdx.x * blockDim.x + threadIdx.x;
    if (i >= n) return;
    int b = batch[i];
    int pb = (i == 0) ? -1 : batch[i - 1];
    for (int k = pb + 1; k <= b; ++k) boff[k] = i;
    if (i == n - 1) {
        for (int k = b + 1; k <= NB; ++k) boff[k] = n;
    }
}

// ---------------- cascade core (32 channels per unit, one wave per node) ----------------
// Lane l: edge j + (l>>3), channels (l&7)*4 .. +3  (float4 gather; 8 lanes = 128 B row
// = one cache line). Pair stream via nontemporal 8 B loads. Edge-phase reduce via
// shfl_xor {8,16,32}; lanes 0-7 hold the full row.

__device__ __forceinline__ float4 gather32(const float* __restrict__ gb, int gstride,
                                           const int2* __restrict__ pairs,
                                           int node, int deg8, int lane) {
    int sub = lane >> 3, cg = lane & 7;
    const long long* pb8 = reinterpret_cast<const long long*>(pairs + (size_t)node * CAP);
    float4 acc = make_float4(0.f, 0.f, 0.f, 0.f);
    if (deg8 > 0) {
        long long pv = __builtin_nontemporal_load(pb8 + sub);
        int j = 0;
        while (true) {
            int src = (int)((unsigned long long)pv & 0xFFFFFFFFull);
            float w = __uint_as_float((unsigned int)((unsigned long long)pv >> 32));
            int jn = j + 8;
            bool more = jn < deg8;
            long long pn = 0;
            if (more) pn = __builtin_nontemporal_load(pb8 + jn + sub);
            float4 gq = *reinterpret_cast<const float4*>(gb + (size_t)src * gstride + cg * 4);
            acc.x += w * gq.x; acc.y += w * gq.y; acc.z += w * gq.z; acc.w += w * gq.w;
            if (!more) break;
            pv = pn; j = jn;
        }
    }
#pragma unroll
    for (int m = 8; m <= 32; m <<= 1) {
        acc.x += __shfl_xor(acc.x, m, 64);
        acc.y += __shfl_xor(acc.y, m, 64);
        acc.z += __shfl_xor(acc.z, m, 64);
        acc.w += __shfl_xor(acc.w, m, 64);
    }
    return acc;
}

// ---- level 1: 2 units (u = ch-half of the 64-ch cascade). Slot g = blockIdx%8 -> XCD.
// unit = g>>2; each slot covers a contiguous quarter of the unit's nodes (balanced).
__global__ __launch_bounds__(256) void cascade_l1(
    const float* __restrict__ x, const float* __restrict__ ubin,
    float* __restrict__ ubout,
    const int2* __restrict__ pairs, const int* __restrict__ cnt,
    const float* __restrict__ dinv, int n, int s,
    float* __restrict__ prevb, float* __restrict__ S1)
{
    int g = blockIdx.x & 7, r = blockIdx.x >> 3;
    int lane = threadIdx.x & 63, widx = threadIdx.x >> 6;
    int q = n >> 2;
    int pos = r * 4 + widx;
    if (pos >= q) return;
    int u = g >> 2;
    int node = (g & 3) * q + pos;
    node = __builtin_amdgcn_readfirstlane(node);

    const float* gb; int gstride;
    if (s == 1) { gb = x + u * 32;                  gstride = 64; }
    else        { gb = ubin + (size_t)u * n * 32;   gstride = 32; }

    int deg = min(cnt[node], CAP);
    int deg8 = (deg + 7) & ~7;
    float dv = dinv[node];
    float selfw = 1.f + dv * dv;

    float4 acc = gather32(gb, gstride, pairs, node, deg8, lane);
    int cg = lane & 7;
    float4 hv = *reinterpret_cast<const float4*>(gb + (size_t)node * gstride + cg * 4);

    if (lane < 8) {
        float4 v;
        v.x = 0.5f * (selfw * hv.x + acc.x);
        v.y = 0.5f * (selfw * hv.y + acc.y);
        v.z = 0.5f * (selfw * hv.z + acc.z);
        v.w = 0.5f * (selfw * hv.w + acc.w);
        *reinterpret_cast<float4*>(ubout + (size_t)u * n * 32 + (size_t)node * 32 + cg * 4) = v;
        float* prow = prevb + (size_t)u * n * 32 + (size_t)node * 32 + cg * 4;
        if (s == 1) {
            *reinterpret_cast<float4*>(prow) = v;
        } else if (s == 2 || s == 4 || s == 8 || s == 16) {
            int slot = (s == 2) ? 0 : (s == 4) ? 1 : (s == 8) ? 2 : 3;
            float4 pv = *reinterpret_cast<const float4*>(prow);
            *reinterpret_cast<float4*>(prow) = v;
            float4 d;
            d.x = fabsf(v.x - pv.x); d.y = fabsf(v.y - pv.y);
            d.z = fabsf(v.z - pv.z); d.w = fabsf(v.w - pv.w);
            *reinterpret_cast<float4*>(S1 + (size_t)node * 256 + slot * 64 + u * 32 + cg * 4) = d;
        }
    }
}

// ---- level 2: 6 units (source block sb = u>>1, half hf = u&1). Balanced slot map:
// each slot g processes 3*q node-steps; slots 1,2,5,6 span two units sequentially.
__global__ __launch_bounds__(256) void cascade_l2(
    const float* __restrict__ S1, const float* __restrict__ ubin,
    float* __restrict__ ubout,
    const int2* __restrict__ pairs, const int* __restrict__ cnt,
    const float* __restrict__ dinv, int n, int s,
    float* __restrict__ prevb, float* __restrict__ S2)
{
    int g = blockIdx.x & 7, r = blockIdx.x >> 3;
    int lane = threadIdx.x & 63, widx = threadIdx.x >> 6;
    int q = n >> 2;
    int pos = r * 4 + widx;
    if (pos >= 3 * q) return;
    int base = (g >= 4) ? 3 : 0;
    int gg = g & 3;
    int u, node;
    if (gg == 0)      { u = base;     node = pos; }
    else if (gg == 1) { if (pos < q)     { u = base;     node = 3 * q + pos; }
                        else             { u = base + 1; node = pos - q; } }
    else if (gg == 2) { if (pos < 2 * q) { u = base + 1; node = 2 * q + pos; }
                        else             { u = base + 2; node = pos - 2 * q; } }
    else              { u = base + 2; node = q + pos; }
    node = __builtin_amdgcn_readfirstlane(node);
    u = __builtin_amdgcn_readfirstlane(u);
    int sb = u >> 1, hf = u & 1;

    const float* gb; int gstride;
    if (s == 1) { gb = S1 + sb * 64 + hf * 32;     gstride = 256; }
    else        { gb = ubin + (size_t)u * n * 32;  gstride = 32; }

    int deg = min(cnt[node], CAP);
    int deg8 = (deg + 7) & ~7;
    float dv = dinv[node];
    float selfw = 1.f + dv * dv;

    float4 acc = gather32(gb, gstride, pairs, node, deg8, lane);
    int cg = lane & 7;
    float4 hv = *reinterpret_cast<const float4*>(gb + (size_t)node * gstride + cg * 4);

    if (lane < 8) {
        float4 v;
        v.x = 0.5f * (selfw * hv.x + acc.x);
        v.y = 0.5f * (selfw * hv.y + acc.y);
        v.z = 0.5f * (selfw * hv.z + acc.z);
        v.w = 0.5f * (selfw * hv.w + acc.w);
        *reinterpret_cast<float4*>(ubout + (size_t)u * n * 32 + (size_t)node * 32 + cg * 4) = v;
        int snap = 2 << sb;  // 2, 4, 8
        float* prow = prevb + (size_t)u * n * 32 + (size_t)node * 32 + cg * 4;
        if (s == snap) {
            *reinterpret_cast<float4*>(prow) = v;
        } else if (s > snap && (s == 4 || s == 8 || s == 16)) {
            int slot;
            if (sb == 0)      slot = (s == 4) ? 0 : (s == 8) ? 1 : 3;
            else if (sb == 1) slot = (s == 8) ? 2 : 4;
            else              slot = 5;
            float4 pv = *reinterpret_cast<const float4*>(prow);
            *reinterpret_cast<float4*>(prow) = v;
            float4 d;
            d.x = fabsf(v.x - pv.x); d.y = fabsf(v.y - pv.y);
            d.z = fabsf(v.z - pv.z); d.w = fabsf(v.w - pv.w);
            *reinterpret_cast<float4*>(S2 + (size_t)node * 384 + slot * 64 + hf * 32 + cg * 4) = d;
        }
    }
}

// ---------------- moments (coalesced two-stage, no atomics) ----------------
// block = (batch b, k-block, node-slice); thread: channel c = tid&63 (fixed),
// sub = tid>>6 strides nodes by 4 -> fully coalesced row reads.

__global__ __launch_bounds__(256) void moments_part(
    const float* __restrict__ x, const float* __restrict__ S1,
    const float* __restrict__ S2, const int* __restrict__ boff,
    double* __restrict__ part)
{
    int bid = blockIdx.x;                    // b * (11*MSLICE) + k * MSLICE + slice
    int slice = bid % MSLICE;
    int k = (bid / MSLICE) % 11;
    int b = bid / (11 * MSLICE);
    int c = threadIdx.x & 63, sub = threadIdx.x >> 6;

    const float* base; int stride;
    if (k == 0)      { base = x  + c;                stride = 64;  }
    else if (k <= 4) { base = S1 + (k - 1) * 64 + c; stride = 256; }
    else             { base = S2 + (k - 5) * 64 + c; stride = 384; }

    int s0 = boff[b], s1e = boff[b + 1];
    int cntb = s1e - s0;
    int per = (cntb + MSLICE - 1) / MSLICE;
    int i0 = s0 + slice * per;
    int i1 = min(s1e, i0 + per);

    double a1 = 0, a2 = 0, a3 = 0, a4 = 0;
    for (int i = i0 + sub; i < i1; i += 4) {
        double v = (double)base[(size_t)i * stride];
        double qq = v * v;
        a1 += v; a2 += qq; a3 += qq * v; a4 += qq * qq;
    }
    int f = k * 64 + c;
    double* qp = part + ((((size_t)slice * 4 + sub) * NB + b) * NFEAT + f) * 4;
    qp[0] = a1; qp[1] = a2; qp[2] = a3; qp[3] = a4;
}

__global__ void finalize_k(const double* __restrict__ part, const int* __restrict__ boff,
                           const float* __restrict__ W, float* __restrict__ out) {
    int i = blockIdx.x * blockDim.x + threadIdx.x;
    if (i < NB * NFEAT) {
        int b = i / NFEAT, f = i % NFEAT;
        double s1 = 0, s2 = 0, s3 = 0, s4 = 0;
        for (int s = 0; s < PSLICE; ++s) {
            const double* qp = part + (((size_t)s * NB + b) * NFEAT + f) * 4;
            s1 += qp[0]; s2 += qp[1]; s3 += qp[2]; s4 += qp[3];
        }
        double cn = (double)max(boff[b + 1] - boff[b], 1);
        double mean = s1 / cn;
        double e2 = s2 / cn, e3 = s3 / cn, e4 = s4 / cn;
        double var = e2 - mean * mean;
        double m3 = e3 - 3.0 * mean * e2 + 2.0 * mean * mean * mean;
        double m4 = e4 - 4.0 * mean * e3 + 6.0 * mean * mean * e2 - 3.0 * mean * mean * mean * mean;
        float skew, kurt;
        if (var > 0.0) {
            double vs = var * sqrt(var);
            skew = (float)(m3 / vs);
            kurt = (float)(m4 / (var * var));
        } else {
            skew = 0.f; kurt = -3.f;
        }
        out[b * 2816 + f]        = (float)mean;
        out[b * 2816 + 704 + f]  = (float)var;
        out[b * 2816 + 1408 + f] = skew;
        out[b * 2816 + 2112 + f] = kurt;
    } else if (i < NB * NFEAT + 68) {
        int j = i - NB * NFEAT;
        out[NB * 2816 + j] = W[j];
    }
}

// ---------------- launch ----------------

extern "C" void kernel_launch(void* const* d_in, const int* in_sizes, int n_in,
                              void* d_out, int out_size, void* d_ws, size_t ws_size,
                              hipStream_t stream) {
    const float* x     = (const float*)d_in[0];
    const int*   ei    = (const int*)d_in[1];
    const int*   batch = (const int*)d_in[2];
    const float* W     = (const float*)d_in[3];
    int N = in_sizes[0] / 64;   // 20000
    int E = in_sizes[1] / 2;    // 640000
    float* out = (float*)d_out;

    char* p = (char*)d_ws;
    auto alloc = [&](size_t bytes) { char* r = p; p += (bytes + 255) & ~255ULL; return r; };
    float* dinv  = (float*)alloc((size_t)N * 4);
    int*   cnt   = (int*)alloc((size_t)N * 4);
    int*   cursor= (int*)alloc((size_t)N * 4);
    int*   boff  = (int*)alloc((NB + 1) * 4);
    double* part = (double*)alloc((size_t)PSLICE * NB * NFEAT * 4 * 8);
    int2*  pairs = (int2*)alloc((size_t)N * CAP * 8);
    float* S1    = (float*)alloc((size_t)N * 256 * 4);
    float* S2    = (float*)alloc((size_t)N * 384 * 4);
    float* bufA  = (float*)alloc((size_t)6 * N * 32 * 4);
    float* bufB  = (float*)alloc((size_t)6 * N * 32 * 4);
    float* prev  = (float*)alloc((size_t)6 * N * 32 * 4);

    hipMemsetAsync(cnt, 0, (size_t)N * 4, stream);
    hipMemsetAsync(cursor, 0, (size_t)N * 4, stream);

    count_edges<<<(E + 255) / 256, 256, 0, stream>>>(ei, E, cnt);
    compute_dinv<<<(N + 255) / 256, 256, 0, stream>>>(cnt, dinv, N);
    fill_edges<<<(E + 255) / 256, 256, 0, stream>>>(ei, E, dinv, cursor, pairs);
    pad_edges<<<(N + 255) / 256, 256, 0, stream>>>(cnt, pairs, N);
    batch_bounds<<<(N + 255) / 256, 256, 0, stream>>>(batch, N, boff);

    int q = N >> 2;
    int grid1 = 8 * ((q + 3) >> 2);          // 2 units * N nodes / 4 waves
    int grid2 = 8 * ((3 * q + 3) >> 2);      // 6 units * N nodes / 4 waves

    // ---- level 1: 2x32-ch units on x; snap s=1; diffs {2,4,8,16} -> S1 slots 0..3 ----
    for (int s = 1; s <= 16; ++s) {
        float* ho = (s & 1) ? bufA : bufB;
        const float* hi = (s & 1) ? bufB : bufA;
        cascade_l1<<<grid1, 256, 0, stream>>>(x, hi, ho, pairs, cnt, dinv, N, s, prev, S1);
    }

    // ---- level 2: 6x32-ch units on S1; per sb: snap {2,4,8}; diffs -> S2 slots 0..5 ----
    for (int s = 1; s <= 16; ++s) {
        float* ho = (s & 1) ? bufA : bufB;
        const float* hi = (s & 1) ? bufB : bufA;
        cascade_l2<<<grid2, 256, 0, stream>>>(S1, hi, ho, pairs, cnt, dinv, N, s, prev, S2);
    }

    moments_part<<<NB * 11 * MSLICE, 256, 0, stream>>>(x, S1, S2, boff, part);

    int fin_threads = NB * NFEAT + 68;
    finalize_k<<<(fin_threads + 255) / 256, 256, 0, stream>>>(part, boff, W, out);
}